// Round 1
// baseline (220.592 us; speedup 1.0000x reference)
//
#include <hip/hip_runtime.h>

#define D 256
#define F4_PER_ROW (D / 4)  // 64 — one float4 per lane

__device__ __forceinline__ float dot4(float4 a, float4 b) {
    return fmaf(a.x, b.x, fmaf(a.y, b.y, fmaf(a.z, b.z, a.w * b.w)));
}

__global__ __launch_bounds__(256) void merge_xs_kernel(
    const float* __restrict__ x0, const float* __restrict__ x1,
    const float* __restrict__ x2, const float* __restrict__ x3,
    const float* __restrict__ w_att, const float* __restrict__ b_att,
    float* __restrict__ emb, float* __restrict__ sc_out, int N)
{
    const int lane = threadIdx.x & 63;
    const int wid  = threadIdx.x >> 6;
    const int wpb  = blockDim.x >> 6;             // waves per block
    const int rstride = gridDim.x * wpb;

    // Per-lane slice of the (L1-resident) weights — hoisted out of row loop.
    const float4 wm = reinterpret_cast<const float4*>(w_att)[lane];       // w_att[0:256]
    const float4 wq = reinterpret_cast<const float4*>(w_att)[64 + lane];  // w_att[256:512]
    const float b = b_att[0];

    for (int row = blockIdx.x * wpb + wid; row < N; row += rstride) {
        const size_t base = (size_t)row * F4_PER_ROW + lane;  // in float4 units
        float4 v0 = reinterpret_cast<const float4*>(x0)[base];
        float4 v1 = reinterpret_cast<const float4*>(x1)[base];
        float4 v2 = reinterpret_cast<const float4*>(x2)[base];
        float4 v3 = reinterpret_cast<const float4*>(x3)[base];

        // 8 per-lane partials: ||x||^2 and the weight dot for each input.
        float r0 = dot4(v0, v0);
        float r1 = dot4(v0, wq);
        float r2 = dot4(v1, v1);
        float r3 = dot4(v1, wm);
        float r4 = dot4(v2, v2);
        float r5 = dot4(v2, wm);
        float r6 = dot4(v3, v3);
        float r7 = dot4(v3, wm);

        // Butterfly reduce all 8 across the 64-lane wave (all lanes get result).
        #pragma unroll
        for (int off = 32; off > 0; off >>= 1) {
            r0 += __shfl_xor(r0, off, 64);
            r1 += __shfl_xor(r1, off, 64);
            r2 += __shfl_xor(r2, off, 64);
            r3 += __shfl_xor(r3, off, 64);
            r4 += __shfl_xor(r4, off, 64);
            r5 += __shfl_xor(r5, off, 64);
            r6 += __shfl_xor(r6, off, 64);
            r7 += __shfl_xor(r7, off, 64);
        }

        const float n0 = fmaxf(sqrtf(r0), 1e-12f);
        const float n1 = fmaxf(sqrtf(r2), 1e-12f);
        const float n2 = fmaxf(sqrtf(r4), 1e-12f);
        const float n3 = fmaxf(sqrtf(r6), 1e-12f);

        const float qterm = r1 / n0 + b;
        float s1 = r3 / n1 + qterm;
        float s2 = r5 / n2 + qterm;
        float s3 = r7 / n3 + qterm;

        // leaky_relu(0.01)
        s1 = s1 > 0.f ? s1 : 0.01f * s1;
        s2 = s2 > 0.f ? s2 : 0.01f * s2;
        s3 = s3 > 0.f ? s3 : 0.01f * s3;

        // softmax over the 3 messages
        const float m  = fmaxf(s1, fmaxf(s2, s3));
        const float e1 = expf(s1 - m);
        const float e2 = expf(s2 - m);
        const float e3 = expf(s3 - m);
        const float inv = 1.0f / (e1 + e2 + e3);
        const float sc1 = e1 * inv, sc2 = e2 * inv, sc3 = e3 * inv;

        // embedding = x0 + sum_l (sc_l / ||x_l||) * x_l
        const float c1 = sc1 / n1, c2 = sc2 / n2, c3 = sc3 / n3;
        float4 o;
        o.x = fmaf(c1, v1.x, fmaf(c2, v2.x, fmaf(c3, v3.x, v0.x)));
        o.y = fmaf(c1, v1.y, fmaf(c2, v2.y, fmaf(c3, v3.y, v0.y)));
        o.z = fmaf(c1, v1.z, fmaf(c2, v2.z, fmaf(c3, v3.z, v0.z)));
        o.w = fmaf(c1, v1.w, fmaf(c2, v2.w, fmaf(c3, v3.w, v0.w)));
        reinterpret_cast<float4*>(emb)[base] = o;

        if (lane == 0) {
            sc_out[row]         = sc1;
            sc_out[N + row]     = sc2;
            sc_out[2 * N + row] = sc3;
        }
    }
}

extern "C" void kernel_launch(void* const* d_in, const int* in_sizes, int n_in,
                              void* d_out, int out_size, void* d_ws, size_t ws_size,
                              hipStream_t stream) {
    const float* x0    = (const float*)d_in[0];
    const float* x1    = (const float*)d_in[1];
    const float* x2    = (const float*)d_in[2];
    const float* x3    = (const float*)d_in[3];
    const float* w_att = (const float*)d_in[4];
    const float* b_att = (const float*)d_in[5];

    const int N = in_sizes[0] / D;  // 200000
    float* emb = (float*)d_out;
    float* sc  = emb + (size_t)N * D;

    const int threads = 256;          // 4 waves -> 4 rows per block
    const int wpb = threads / 64;
    int blocks = (N + wpb - 1) / wpb;
    if (blocks > 4096) blocks = 4096; // grid-stride handles the rest

    merge_xs_kernel<<<blocks, threads, 0, stream>>>(x0, x1, x2, x3, w_att, b_att,
                                                    emb, sc, N);
}

// Round 3
// 206.300 us; speedup vs baseline: 1.0693x; 1.0693x over previous
//
#include <hip/hip_runtime.h>

#define D 256
#define F4_PER_ROW (D / 4)  // 64 float4 per row

typedef float fx4 __attribute__((ext_vector_type(4)));  // native vec for nontemporal builtin

__device__ __forceinline__ float dot4(float4 a, float4 b) {
    return fmaf(a.x, b.x, fmaf(a.y, b.y, fmaf(a.z, b.z, a.w * b.w)));
}

__device__ __forceinline__ void nt_store4(float4 v, float4* p) {
    fx4 t; t.x = v.x; t.y = v.y; t.z = v.z; t.w = v.w;
    __builtin_nontemporal_store(t, reinterpret_cast<fx4*>(p));
}

// 2 rows per wave: lanes 0-31 handle row 2u, lanes 32-63 handle row 2u+1.
// Each lane holds 2 float4 (8 floats) of each of the 4 inputs.
__global__ __launch_bounds__(256) void merge_xs_kernel(
    const float* __restrict__ x0, const float* __restrict__ x1,
    const float* __restrict__ x2, const float* __restrict__ x3,
    const float* __restrict__ w_att, const float* __restrict__ b_att,
    float* __restrict__ emb, float* __restrict__ sc_out, int N)
{
    const int lane = threadIdx.x & 63;
    const int sub  = lane & 31;       // lane within the row's 32-lane group
    const int half = lane >> 5;       // which of the wave's 2 rows
    const int wid  = threadIdx.x >> 6;
    const int wpb  = blockDim.x >> 6;
    const int nwaves = gridDim.x * wpb;
    const int gw   = blockIdx.x * wpb + wid;

    const float4* x0f = reinterpret_cast<const float4*>(x0);
    const float4* x1f = reinterpret_cast<const float4*>(x1);
    const float4* x2f = reinterpret_cast<const float4*>(x2);
    const float4* x3f = reinterpret_cast<const float4*>(x3);
    float4* embf      = reinterpret_cast<float4*>(emb);

    // Per-lane weight slices (L1-resident), hoisted.
    const float4* wmf = reinterpret_cast<const float4*>(w_att);  // w_att[0:256]
    const float4* wqf = wmf + 32 * 2;                            // w_att[256:512]
    const float4 wma = wmf[sub], wmb = wmf[sub + 32];
    const float4 wqa = wqf[sub], wqb = wqf[sub + 32];
    const float b = b_att[0];

    const int nUnits = (N + 1) >> 1;  // 2-row units

    for (int unit = gw; unit < nUnits; unit += nwaves) {
        const int row = unit * 2 + half;
        const bool valid = row < N;
        const size_t base = valid ? ((size_t)row * F4_PER_ROW + sub) : (size_t)sub;

        float4 v0a = x0f[base], v0b = x0f[base + 32];
        float4 v1a = x1f[base], v1b = x1f[base + 32];
        float4 v2a = x2f[base], v2b = x2f[base + 32];
        float4 v3a = x3f[base], v3b = x3f[base + 32];

        // 8 per-lane partials: ||x||^2 and weight-dot for each input.
        float r0 = dot4(v0a, v0a) + dot4(v0b, v0b);
        float r1 = dot4(v0a, wqa) + dot4(v0b, wqb);
        float r2 = dot4(v1a, v1a) + dot4(v1b, v1b);
        float r3 = dot4(v1a, wma) + dot4(v1b, wmb);
        float r4 = dot4(v2a, v2a) + dot4(v2b, v2b);
        float r5 = dot4(v2a, wma) + dot4(v2b, wmb);
        float r6 = dot4(v3a, v3a) + dot4(v3b, v3b);
        float r7 = dot4(v3a, wma) + dot4(v3b, wmb);

        // Butterfly over 32 lanes (offsets < 32 stay within each half-wave).
        #pragma unroll
        for (int off = 16; off > 0; off >>= 1) {
            r0 += __shfl_xor(r0, off, 64);
            r1 += __shfl_xor(r1, off, 64);
            r2 += __shfl_xor(r2, off, 64);
            r3 += __shfl_xor(r3, off, 64);
            r4 += __shfl_xor(r4, off, 64);
            r5 += __shfl_xor(r5, off, 64);
            r6 += __shfl_xor(r6, off, 64);
            r7 += __shfl_xor(r7, off, 64);
        }

        const float n0 = fmaxf(sqrtf(r0), 1e-12f);
        const float n1 = fmaxf(sqrtf(r2), 1e-12f);
        const float n2 = fmaxf(sqrtf(r4), 1e-12f);
        const float n3 = fmaxf(sqrtf(r6), 1e-12f);

        const float qterm = r1 / n0 + b;
        float s1 = r3 / n1 + qterm;
        float s2 = r5 / n2 + qterm;
        float s3 = r7 / n3 + qterm;

        // leaky_relu(0.01)
        s1 = s1 > 0.f ? s1 : 0.01f * s1;
        s2 = s2 > 0.f ? s2 : 0.01f * s2;
        s3 = s3 > 0.f ? s3 : 0.01f * s3;

        // softmax over the 3 messages
        const float m  = fmaxf(s1, fmaxf(s2, s3));
        const float e1 = expf(s1 - m);
        const float e2 = expf(s2 - m);
        const float e3 = expf(s3 - m);
        const float inv = 1.0f / (e1 + e2 + e3);
        const float sc1 = e1 * inv, sc2 = e2 * inv, sc3 = e3 * inv;

        // embedding = x0 + sum_l (sc_l / ||x_l||) * x_l
        const float c1 = sc1 / n1, c2 = sc2 / n2, c3 = sc3 / n3;
        float4 oa, ob;
        oa.x = fmaf(c1, v1a.x, fmaf(c2, v2a.x, fmaf(c3, v3a.x, v0a.x)));
        oa.y = fmaf(c1, v1a.y, fmaf(c2, v2a.y, fmaf(c3, v3a.y, v0a.y)));
        oa.z = fmaf(c1, v1a.z, fmaf(c2, v2a.z, fmaf(c3, v3a.z, v0a.z)));
        oa.w = fmaf(c1, v1a.w, fmaf(c2, v2a.w, fmaf(c3, v3a.w, v0a.w)));
        ob.x = fmaf(c1, v1b.x, fmaf(c2, v2b.x, fmaf(c3, v3b.x, v0b.x)));
        ob.y = fmaf(c1, v1b.y, fmaf(c2, v2b.y, fmaf(c3, v3b.y, v0b.y)));
        ob.z = fmaf(c1, v1b.z, fmaf(c2, v2b.z, fmaf(c3, v3b.z, v0b.z)));
        ob.w = fmaf(c1, v1b.w, fmaf(c2, v2b.w, fmaf(c3, v3b.w, v0b.w)));

        if (valid) {
            nt_store4(oa, &embf[base]);
            nt_store4(ob, &embf[base + 32]);
            if (sub == 0) {
                __builtin_nontemporal_store(sc1, &sc_out[row]);
                __builtin_nontemporal_store(sc2, &sc_out[N + row]);
                __builtin_nontemporal_store(sc3, &sc_out[2 * N + row]);
            }
        }
    }
}

extern "C" void kernel_launch(void* const* d_in, const int* in_sizes, int n_in,
                              void* d_out, int out_size, void* d_ws, size_t ws_size,
                              hipStream_t stream) {
    const float* x0    = (const float*)d_in[0];
    const float* x1    = (const float*)d_in[1];
    const float* x2    = (const float*)d_in[2];
    const float* x3    = (const float*)d_in[3];
    const float* w_att = (const float*)d_in[4];
    const float* b_att = (const float*)d_in[5];

    const int N = in_sizes[0] / D;  // 200000
    float* emb = (float*)d_out;
    float* sc  = emb + (size_t)N * D;

    const int threads = 256;            // 4 waves/block, 2 rows/wave
    const int wpb = threads / 64;
    const int nUnits = (N + 1) / 2;     // 100000
    int blocks = (nUnits + wpb - 1) / wpb;
    if (blocks > 4096) blocks = 4096;   // grid-stride handles the rest

    merge_xs_kernel<<<blocks, threads, 0, stream>>>(x0, x1, x2, x3, w_att, b_att,
                                                    emb, sc, N);
}

// Round 4
// 185.895 us; speedup vs baseline: 1.1866x; 1.1098x over previous
//
#include <hip/hip_runtime.h>

#define D 256
#define F4_PER_ROW (D / 4)  // 64 float4 per row

typedef float fx4 __attribute__((ext_vector_type(4)));  // native vec for nontemporal builtin

__device__ __forceinline__ float dot4(float4 a, float4 b) {
    return fmaf(a.x, b.x, fmaf(a.y, b.y, fmaf(a.z, b.z, a.w * b.w)));
}

__device__ __forceinline__ void nt_store4(float4 v, float4* p) {
    fx4 t; t.x = v.x; t.y = v.y; t.z = v.z; t.w = v.w;
    __builtin_nontemporal_store(t, reinterpret_cast<fx4*>(p));
}

// One 2-row unit per wave: lanes 0-31 -> row 2u, lanes 32-63 -> row 2u+1.
// Each lane holds 2 float4 (8 floats) of each of the 4 inputs. No loop:
// TLP from 100k waves keeps loads continuously in flight.
__global__ __launch_bounds__(256) void merge_xs_kernel(
    const float* __restrict__ x0, const float* __restrict__ x1,
    const float* __restrict__ x2, const float* __restrict__ x3,
    const float* __restrict__ w_att, const float* __restrict__ b_att,
    float* __restrict__ emb, float* __restrict__ sc_out, int N)
{
    const int lane = threadIdx.x & 63;
    const int sub  = lane & 31;       // lane within the row's 32-lane group
    const int half = lane >> 5;       // which of the wave's 2 rows
    const int wid  = threadIdx.x >> 6;
    const int wpb  = blockDim.x >> 6;

    const int nUnits = (N + 1) >> 1;
    const int unit = blockIdx.x * wpb + wid;
    if (unit >= nUnits) return;

    const int row = unit * 2 + half;
    const bool valid = row < N;
    const size_t base = valid ? ((size_t)row * F4_PER_ROW + sub) : (size_t)sub;

    const float4* x0f = reinterpret_cast<const float4*>(x0);
    const float4* x1f = reinterpret_cast<const float4*>(x1);
    const float4* x2f = reinterpret_cast<const float4*>(x2);
    const float4* x3f = reinterpret_cast<const float4*>(x3);
    float4* embf      = reinterpret_cast<float4*>(emb);

    // Input loads first — get them in flight immediately.
    float4 v0a = x0f[base], v0b = x0f[base + 32];
    float4 v1a = x1f[base], v1b = x1f[base + 32];
    float4 v2a = x2f[base], v2b = x2f[base + 32];
    float4 v3a = x3f[base], v3b = x3f[base + 32];

    // Weight slices (L1/L2-resident).
    const float4* wmf = reinterpret_cast<const float4*>(w_att);  // w_att[0:256]
    const float4* wqf = wmf + 64;                                // w_att[256:512]
    const float4 wma = wmf[sub], wmb = wmf[sub + 32];
    const float4 wqa = wqf[sub], wqb = wqf[sub + 32];
    const float b = b_att[0];

    // 8 per-lane partials: ||x||^2 and weight-dot for each input.
    float r0 = dot4(v0a, v0a) + dot4(v0b, v0b);
    float r1 = dot4(v0a, wqa) + dot4(v0b, wqb);
    float r2 = dot4(v1a, v1a) + dot4(v1b, v1b);
    float r3 = dot4(v1a, wma) + dot4(v1b, wmb);
    float r4 = dot4(v2a, v2a) + dot4(v2b, v2b);
    float r5 = dot4(v2a, wma) + dot4(v2b, wmb);
    float r6 = dot4(v3a, v3a) + dot4(v3b, v3b);
    float r7 = dot4(v3a, wma) + dot4(v3b, wmb);

    // Butterfly over 32 lanes (offsets < 32 stay within each half-wave).
    #pragma unroll
    for (int off = 16; off > 0; off >>= 1) {
        r0 += __shfl_xor(r0, off, 64);
        r1 += __shfl_xor(r1, off, 64);
        r2 += __shfl_xor(r2, off, 64);
        r3 += __shfl_xor(r3, off, 64);
        r4 += __shfl_xor(r4, off, 64);
        r5 += __shfl_xor(r5, off, 64);
        r6 += __shfl_xor(r6, off, 64);
        r7 += __shfl_xor(r7, off, 64);
    }

    const float n0 = fmaxf(sqrtf(r0), 1e-12f);
    const float n1 = fmaxf(sqrtf(r2), 1e-12f);
    const float n2 = fmaxf(sqrtf(r4), 1e-12f);
    const float n3 = fmaxf(sqrtf(r6), 1e-12f);

    const float qterm = r1 / n0 + b;
    float s1 = r3 / n1 + qterm;
    float s2 = r5 / n2 + qterm;
    float s3 = r7 / n3 + qterm;

    // leaky_relu(0.01)
    s1 = s1 > 0.f ? s1 : 0.01f * s1;
    s2 = s2 > 0.f ? s2 : 0.01f * s2;
    s3 = s3 > 0.f ? s3 : 0.01f * s3;

    // softmax over the 3 messages
    const float m  = fmaxf(s1, fmaxf(s2, s3));
    const float e1 = expf(s1 - m);
    const float e2 = expf(s2 - m);
    const float e3 = expf(s3 - m);
    const float inv = 1.0f / (e1 + e2 + e3);
    const float sc1 = e1 * inv, sc2 = e2 * inv, sc3 = e3 * inv;

    // embedding = x0 + sum_l (sc_l / ||x_l||) * x_l
    const float c1 = sc1 / n1, c2 = sc2 / n2, c3 = sc3 / n3;
    float4 oa, ob;
    oa.x = fmaf(c1, v1a.x, fmaf(c2, v2a.x, fmaf(c3, v3a.x, v0a.x)));
    oa.y = fmaf(c1, v1a.y, fmaf(c2, v2a.y, fmaf(c3, v3a.y, v0a.y)));
    oa.z = fmaf(c1, v1a.z, fmaf(c2, v2a.z, fmaf(c3, v3a.z, v0a.z)));
    oa.w = fmaf(c1, v1a.w, fmaf(c2, v2a.w, fmaf(c3, v3a.w, v0a.w)));
    ob.x = fmaf(c1, v1b.x, fmaf(c2, v2b.x, fmaf(c3, v3b.x, v0b.x)));
    ob.y = fmaf(c1, v1b.y, fmaf(c2, v2b.y, fmaf(c3, v3b.y, v0b.y)));
    ob.z = fmaf(c1, v1b.z, fmaf(c2, v2b.z, fmaf(c3, v3b.z, v0b.z)));
    ob.w = fmaf(c1, v1b.w, fmaf(c2, v2b.w, fmaf(c3, v3b.w, v0b.w)));

    if (valid) {
        nt_store4(oa, &embf[base]);
        nt_store4(ob, &embf[base + 32]);
        if (sub == 0) {
            __builtin_nontemporal_store(sc1, &sc_out[row]);
            __builtin_nontemporal_store(sc2, &sc_out[N + row]);
            __builtin_nontemporal_store(sc3, &sc_out[2 * N + row]);
        }
    }
}

extern "C" void kernel_launch(void* const* d_in, const int* in_sizes, int n_in,
                              void* d_out, int out_size, void* d_ws, size_t ws_size,
                              hipStream_t stream) {
    const float* x0    = (const float*)d_in[0];
    const float* x1    = (const float*)d_in[1];
    const float* x2    = (const float*)d_in[2];
    const float* x3    = (const float*)d_in[3];
    const float* w_att = (const float*)d_in[4];
    const float* b_att = (const float*)d_in[5];

    const int N = in_sizes[0] / D;  // 200000
    float* emb = (float*)d_out;
    float* sc  = emb + (size_t)N * D;

    const int threads = 256;                 // 4 waves/block, 2 rows/wave
    const int wpb = threads / 64;
    const int nUnits = (N + 1) / 2;          // 100000
    const int blocks = (nUnits + wpb - 1) / wpb;  // 25000 — one unit per wave

    merge_xs_kernel<<<blocks, threads, 0, stream>>>(x0, x1, x2, x3, w_att, b_att,
                                                    emb, sc, N);
}